// Round 20
// baseline (1010.899 us; speedup 1.0000x reference)
//
#include <hip/hip_runtime.h>
#include <math.h>

#define TT 2048
#define HH 64
#define NE 2       // batch elems per block
#define NBLK 256   // 512 / NE -> all 256 CUs
#define NTHR 256   // 4 waves, all symmetric

typedef _Float16 half8 __attribute__((ext_vector_type(8)));
typedef float f32x4 __attribute__((ext_vector_type(4)));

__device__ __forceinline__ float sigmoid_fast(float x) {
    float e = __expf(-x);
    return __builtin_amdgcn_rcpf(1.0f + e);
}
__device__ __forceinline__ float tanh_fast(float x) {
    float e = __expf(-2.0f * x);
    return fmaf(2.0f, __builtin_amdgcn_rcpf(1.0f + e), -1.0f);
}
// select element r (runtime, per-lane-constant) from f32x4 via cndmask —
// static element indices only (rule #20: no scratch).
__device__ __forceinline__ float sel4(f32x4 v, int r) {
    float s01 = (r & 1) ? v[1] : v[0];
    float s23 = (r & 1) ? v[3] : v[2];
    return (r & 2) ? s23 : s01;
}

// Round 20: 4 symmetric waves, NE=2, 256 blocks (all CUs), in-register gates.
// Wall = step x 2049 (blocks concurrent), so minimize STEP: wave j computes
// BOTH layers for unit group j (8 Whh0 + 16 Wih1/Whh1 MFMAs); B-cols alias
// c -> elem c&1, so the 16 C-cols encode (L=e16>>3, rsel=(e16>>1)&3,
// ae=e16&1): all 64 lanes own exactly one (layer,unit,elem) -> 10 trans/lane,
// ZERO gate LDS (r19's win generalized), perfectly balanced 4-wave barrier.
// 1 wave/SIMD -> VGPR budget 512: the 24-frag (96 VGPR) pinned set fits (r13
// spilled only because of the 128 cap). Same per-gate MFMA order/operands as
// r19 -> absmax must stay 4.882812e-4 exactly.
__global__ __launch_bounds__(NTHR) __attribute__((amdgpu_waves_per_eu(1, 1)))
void lstm_sym4_kernel(const float* __restrict__ x,      // [B,T]
                      const float* __restrict__ w_ih0,  // [256,1]
                      const float* __restrict__ w_hh0,  // [256,64]
                      const float* __restrict__ b_ih0,  // [256]
                      const float* __restrict__ b_hh0,  // [256]
                      const float* __restrict__ w_ih1,  // [256,64]
                      const float* __restrict__ w_hh1,  // [256,64]
                      const float* __restrict__ b_ih1,  // [256]
                      const float* __restrict__ b_hh1,  // [256]
                      const float* __restrict__ w1, const float* __restrict__ b1,
                      const float* __restrict__ w2, const float* __restrict__ b2,
                      const float* __restrict__ w3, const float* __restrict__ b3,
                      float* __restrict__ out)          // [B,10]
{
    const int tid = threadIdx.x;
    const int wv  = tid >> 6;        // wave 0..3
    const int l   = tid & 63;
    const int j   = wv;              // unit group [16j, 16j+16), both layers
    const int e16 = l & 15;          // MFMA col
    const int kg  = l >> 4;          // k-group / C row-quad
    const int bA  = blockIdx.x * NE;

    __shared__ __align__(16) float xs[(TT + 1) * (NE + 1)];    // [t][3] pad
    __shared__ __align__(16) _Float16 hsw[2][2][16 * 64];      // [L][parity] swizzled
    __shared__ float cls1[NE][HH];
    __shared__ float cls2[NE][32];

    for (int i = tid; i < 2 * 2 * 16 * 64; i += NTHR)
        ((_Float16*)hsw)[i] = (_Float16)0.0f;
    // stage x: xs[t*3+e] (stride-3 conflict-free), coalesced reads; pad t=TT
    for (int i = tid; i < NE * TT; i += NTHR) {
        const int e = i >> 11, t = i & (TT - 1);
        xs[t * (NE + 1) + e] = x[(size_t)(bA + e) * TT + t];
    }
    if (tid < NE + 1) xs[TT * (NE + 1) + tid] = 0.0f;

    // ---- weight A-frags (fp16): 24 half8 = 96 VGPR ----
    // w0f[2g+kc]  = Whh0(g,j)   -> gates0, 2-deep
    // wif[2g+kc]  = Wih1(g,j) ; whf[2g+kc] = Whh1(g,j) -> gates1, 4-deep
    half8 w0f[8], wif[8], whf[8];
    {
        auto frag = [&](const float* M, int g, int kc) {
            const int row = g * 64 + 16 * j + e16;   // A-frag row = l&15
            half8 v;
            #pragma unroll
            for (int i = 0; i < 8; ++i) v[i] = (_Float16)M[row * HH + kc * 32 + kg * 8 + i];
            return v;
        };
        #pragma unroll
        for (int g = 0; g < 4; ++g) {
            w0f[2 * g + 0] = frag(w_hh0, g, 0);
            w0f[2 * g + 1] = frag(w_hh0, g, 1);
            wif[2 * g + 0] = frag(w_ih1, g, 0);
            wif[2 * g + 1] = frag(w_ih1, g, 1);
            whf[2 * g + 0] = frag(w_hh1, g, 0);
            whf[2 * g + 1] = frag(w_hh1, g, 1);
        }
    }

    // ---- act identity: lane owns (Lsel, unit au, elem ae) IN-REGISTER ----
    const int Lsel = e16 >> 3;           // cols 0-7 -> L0, 8-15 -> L1
    const int rsel = (e16 >> 1) & 3;     // C-row quad offset
    const int ae   = e16 & 1;            // elem (= aliased B column content)
    const int au   = 16 * j + 4 * kg + rsel;
    float bi[4], wxr[4];
    {
        const float* bihp = Lsel ? b_ih1 : b_ih0;
        const float* bhhp = Lsel ? b_hh1 : b_hh0;
        #pragma unroll
        for (int g = 0; g < 4; ++g) {
            bi[g]  = bihp[g * 64 + au] + bhhp[g * 64 + au];
            wxr[g] = Lsel ? 0.0f : w_ih0[g * 64 + au];
        }
    }
    // pin (rounds 1-4 lesson: allocator rematerializes weight loads otherwise)
    #pragma unroll
    for (int i = 0; i < 8; ++i) {
        asm volatile("" : "+v"(w0f[i]));
        asm volatile("" : "+v"(wif[i]));
        asm volatile("" : "+v"(whf[i]));
    }
    #pragma unroll
    for (int g = 0; g < 4; ++g) {
        asm volatile("" : "+v"(bi[g]));
        asm volatile("" : "+v"(wxr[g]));
    }

    float c = 0.0f;                      // lane's cell state (Lsel, au, ae)

    // B-frag address: col c reads elem c&1 (2-way duplicate columns)
    const int swz  = ae << 4;            // (ae&7)<<4
    const int hro0 = ae * 128 + ((16 * kg) ^ swz);           // k-chunk 0
    const int hro1 = ae * 128 + ((64 + 16 * kg) ^ swz);      // k-chunk 1
    const int hwb  = ae * 128 + ((2 * au) ^ swz);            // act h write byte
    const f32x4 z4 = {0.0f, 0.0f, 0.0f, 0.0f};

    __syncthreads();

    for (int t = 0; t <= TT; ++t) {
        const int rp = t & 1;            // read parity
        // ---- MFMA: gates0(t) [2-deep] and gates1(t-1) [4-deep], raw ----
        const char* h0r = (const char*)&hsw[0][rp][0];
        const char* h1r = (const char*)&hsw[1][rp][0];
        half8 f0 = *(const half8*)(h0r + hro0);
        half8 f1 = *(const half8*)(h0r + hro1);
        half8 f2 = *(const half8*)(h1r + hro0);
        half8 f3 = *(const half8*)(h1r + hro1);
        f32x4 a0[4], a1[4];
        #pragma unroll
        for (int g = 0; g < 4; ++g) {
            a0[g] = __builtin_amdgcn_mfma_f32_16x16x32_f16(w0f[2 * g + 0], f0, z4, 0, 0, 0);
            a1[g] = __builtin_amdgcn_mfma_f32_16x16x32_f16(wif[2 * g + 0], f0, z4, 0, 0, 0);
            a0[g] = __builtin_amdgcn_mfma_f32_16x16x32_f16(w0f[2 * g + 1], f1, a0[g], 0, 0, 0);
            a1[g] = __builtin_amdgcn_mfma_f32_16x16x32_f16(wif[2 * g + 1], f1, a1[g], 0, 0, 0);
            a1[g] = __builtin_amdgcn_mfma_f32_16x16x32_f16(whf[2 * g + 0], f2, a1[g], 0, 0, 0);
            a1[g] = __builtin_amdgcn_mfma_f32_16x16x32_f16(whf[2 * g + 1], f3, a1[g], 0, 0, 0);
        }
        // ---- act directly from registers (1 unit-elem/lane, 10 trans) ----
        {
            float z0 = Lsel ? sel4(a1[0], rsel) : sel4(a0[0], rsel);
            float z1 = Lsel ? sel4(a1[1], rsel) : sel4(a0[1], rsel);
            float z2 = Lsel ? sel4(a1[2], rsel) : sel4(a0[2], rsel);
            float z3 = Lsel ? sel4(a1[3], rsel) : sel4(a0[3], rsel);
            const float xt = xs[t * (NE + 1) + ae];
            z0 += fmaf(wxr[0], xt, bi[0]);
            z1 += fmaf(wxr[1], xt, bi[1]);
            z2 += fmaf(wxr[2], xt, bi[2]);
            z3 += fmaf(wxr[3], xt, bi[3]);
            float gi = sigmoid_fast(z0);
            float gf = sigmoid_fast(z1);
            float gg = tanh_fast(z2);
            float go = sigmoid_fast(z3);
            c = fmaf(gf, c, gi * gg);
            float h = go * tanh_fast(c);
            if (Lsel && t == 0) { c = 0.0f; h = 0.0f; }   // enforce h1(-1)=0
            *(_Float16*)((char*)&hsw[Lsel][rp ^ 1][0] + hwb) = (_Float16)h;
        }
        __syncthreads();
    }
    // h_last = h1(TT-1), written at t=TT into parity (TT&1)^1 = 1

    // ---- classifier head: wave wv<NE handles elem wv ----
    if (wv < NE) {
        const char* h1f = (const char*)&hsw[1][1][0];
        float a = b1[l];
        #pragma unroll 8
        for (int k = 0; k < HH; ++k) {
            const float hk = (float)*(const _Float16*)(h1f + wv * 128 + ((2 * k) ^ (wv << 4)));
            a = fmaf(w1[l * HH + k], hk, a);
        }
        cls1[wv][l] = fmaxf(a, 0.0f);
    }
    __syncthreads();
    if (wv < NE && l < 32) {
        float a = b2[l];
        #pragma unroll 8
        for (int k = 0; k < HH; ++k) a = fmaf(w2[l * HH + k], cls1[wv][k], a);
        cls2[wv][l] = fmaxf(a, 0.0f);
    }
    __syncthreads();
    if (wv < NE && l < 10) {
        float a = b3[l];
        #pragma unroll
        for (int k = 0; k < 32; ++k) a = fmaf(w3[l * 32 + k], cls2[wv][k], a);
        out[(size_t)(bA + wv) * 10 + l] = a;
    }
}

extern "C" void kernel_launch(void* const* d_in, const int* in_sizes, int n_in,
                              void* d_out, int out_size, void* d_ws, size_t ws_size,
                              hipStream_t stream) {
    const float* x     = (const float*)d_in[0];
    const float* w_ih0 = (const float*)d_in[1];
    const float* w_hh0 = (const float*)d_in[2];
    const float* b_ih0 = (const float*)d_in[3];
    const float* b_hh0 = (const float*)d_in[4];
    const float* w_ih1 = (const float*)d_in[5];
    const float* w_hh1 = (const float*)d_in[6];
    const float* b_ih1 = (const float*)d_in[7];
    const float* b_hh1 = (const float*)d_in[8];
    const float* w1    = (const float*)d_in[9];
    const float* b1    = (const float*)d_in[10];
    const float* w2    = (const float*)d_in[11];
    const float* b2    = (const float*)d_in[12];
    const float* w3    = (const float*)d_in[13];
    const float* b3    = (const float*)d_in[14];
    float* out = (float*)d_out;

    lstm_sym4_kernel<<<NBLK, NTHR, 0, stream>>>(x, w_ih0, w_hh0, b_ih0, b_hh0,
                                                w_ih1, w_hh1, b_ih1, b_hh1,
                                                w1, b1, w2, b2, w3, b3, out);
}